// Round 2
// baseline (4069.024 us; speedup 1.0000x reference)
//
#include <hip/hip_runtime.h>
#include <math.h>

// LSTMPredictor: B=2048 rows, 3x LSTMCell(H=50), P=17, T=512 + 32 future steps.
// Reference is fp32; buffer dtype (fp32 vs bf16) is sniffed at runtime on-device
// (round-1 NaN proved the buffers are NOT what round 0 assumed). One block per CU
// owns M=8 batch rows for the whole 544-step recurrence. Weights live in per-thread
// REGISTERS (fp32, full precision); h-state in LDS; c-state in registers of the
// (m,j) update thread. No grid-wide sync needed (rows independent).

#define BATCH    2048
#define PP       17
#define HH       50
#define GG       200      // 4*H
#define MROWS    8
#define NTHREADS 512
#define NBLOCKS  (BATCH / MROWS)   // 256

__device__ __forceinline__ float bf2f(unsigned short u) {
    unsigned int i = ((unsigned int)u) << 16;
    float f; __builtin_memcpy(&f, &i, 4); return f;
}
__device__ __forceinline__ unsigned short f2bf(float f) {
    unsigned int i; __builtin_memcpy(&i, &f, 4);
    return (unsigned short)((i + 0x7fffu + ((i >> 16) & 1u)) >> 16);
}
// dtype-flag-aware global load of element i
__device__ __forceinline__ float ldin(const void* p, long i, bool f32) {
    return f32 ? ((const float*)p)[i] : bf2f(((const unsigned short*)p)[i]);
}
__device__ __forceinline__ float fsig(float x) { return 1.0f / (1.0f + expf(-x)); }

// ---- dtype sniffer: bf16 weights decode to |v|<=0.142; fp32-as-bf16 gives junk ----
extern "C" __global__ void sniff_dtype(const unsigned short* __restrict__ w,
                                       int* __restrict__ flag) {
    int lane = threadIdx.x;          // 64 lanes, read first 256 shorts
    bool bad = false;
#pragma unroll
    for (int t = 0; t < 4; ++t) {
        float v = bf2f(w[lane * 4 + t]);
        bad |= !(fabsf(v) <= 1.0f);  // catches NaN/inf/large
    }
    unsigned long long m = __ballot(bad);
    if (lane == 0) flag[0] = (m != 0ULL) ? 1 : 0;   // 1 => fp32 buffers
}

// gate phase: thread (g,half) accumulates its K-half of gate g for all 8 rows.
// Weights come from registers (w[t], constant-indexed via full unroll).
template <int TRIPS>
__device__ __forceinline__ void gate_phase(const float* __restrict__ S,
                                           float* __restrict__ gb,
                                           const float* __restrict__ w,
                                           float bias, int srow, int g, int half) {
    if (g < GG) {
        float b = half ? 0.0f : bias;
        float a0 = b, a1 = b, a2 = b, a3 = b, a4 = b, a5 = b, a6 = b, a7 = b;
        const float4* Sp = (const float4*)(S + (srow + half * TRIPS) * MROWS);
#pragma unroll
        for (int t = 0; t < TRIPS; ++t) {
            float wv = w[t];
            float4 lo = Sp[2 * t];        // wave-uniform address -> LDS broadcast
            float4 hi = Sp[2 * t + 1];
            a0 = fmaf(wv, lo.x, a0); a1 = fmaf(wv, lo.y, a1);
            a2 = fmaf(wv, lo.z, a2); a3 = fmaf(wv, lo.w, a3);
            a4 = fmaf(wv, hi.x, a4); a5 = fmaf(wv, hi.y, a5);
            a6 = fmaf(wv, hi.z, a6); a7 = fmaf(wv, hi.w, a7);
        }
        float* go = gb + half * 1600 + g;           // [half][m][g]
        go[0]    = a0; go[200]  = a1; go[400]  = a2; go[600]  = a3;
        go[800]  = a4; go[1000] = a5; go[1200] = a6; go[1400] = a7;
    }
}

__device__ __forceinline__ void lstm_update(float* __restrict__ S,
                                            const float* __restrict__ gb,
                                            float& c, int hrow, int tid) {
    // caller guards tid < 400;  task = (m = tid/50, j = tid%50)
    int m = tid / 50;
    int j = tid - m * 50;
    const float* g0 = gb + m * GG + j;
    const float* g1 = g0 + 1600;
    float ii = g0[0]   + g1[0];
    float ff = g0[50]  + g1[50];
    float gg = g0[100] + g1[100];
    float oo = g0[150] + g1[150];
    float cn = fsig(ff) * c + fsig(ii) * tanhf(gg);
    c = cn;
    S[(hrow + j) * MROWS + m] = fsig(oo) * tanhf(cn);
}

extern "C" __global__ void __launch_bounds__(NTHREADS, 2)
lstm_persistent(const void* __restrict__ x,
                const void* __restrict__ wih1, const void* __restrict__ whh1,
                const void* __restrict__ bih1, const void* __restrict__ bhh1,
                const void* __restrict__ wih2, const void* __restrict__ whh2,
                const void* __restrict__ bih2, const void* __restrict__ bhh2,
                const void* __restrict__ wih3, const void* __restrict__ whh3,
                const void* __restrict__ bih3, const void* __restrict__ bhh3,
                const void* __restrict__ wlin, const void* __restrict__ blin,
                void* __restrict__ out, const int* __restrict__ flag,
                int T, int steps)
{
    const int tid = threadIdx.x;
    __shared__ float S[167 * MROWS];   // rows: 0..16 x_t | 17..66 h1 | 67..116 h2 | 117..166 h3
    __shared__ float gb[2 * MROWS * GG];
    __shared__ float WLt[50 * PP];     // W_lin^T (fp32)

    const bool f32 = (flag[0] != 0);

    const int g = tid & 255;
    const int half = tid >> 8;

    // ---- per-thread register weights (fp32, full precision) ----
    float w1[34], w2[50], w3[50];
    if (g < GG) {
        if (half == 0) {               // cell1 k = 0..33  (x 0..16 | h1 cols 0..16)
#pragma unroll
            for (int t = 0; t < 17; ++t) w1[t] = ldin(wih1, (long)g * 17 + t, f32);
#pragma unroll
            for (int t = 17; t < 34; ++t) w1[t] = ldin(whh1, (long)g * 50 + (t - 17), f32);
        } else {                       // cell1 k = 34..67 (h1 cols 17..49 | zero pad)
#pragma unroll
            for (int t = 0; t < 33; ++t) w1[t] = ldin(whh1, (long)g * 50 + 17 + t, f32);
            w1[33] = 0.0f;
        }
#pragma unroll
        for (int t = 0; t < 50; ++t)
            w2[t] = ldin(half ? whh2 : wih2, (long)g * 50 + t, f32);
#pragma unroll
        for (int t = 0; t < 50; ++t)
            w3[t] = ldin(half ? whh3 : wih3, (long)g * 50 + t, f32);
    }
    // combined biases (used by half==0 threads only)
    float b1 = 0.0f, b2 = 0.0f, b3 = 0.0f;
    if (g < GG && half == 0) {
        b1 = ldin(bih1, g, f32) + ldin(bhh1, g, f32);
        b2 = ldin(bih2, g, f32) + ldin(bhh2, g, f32);
        b3 = ldin(bih3, g, f32) + ldin(bhh3, g, f32);
    }
    // linear-head bias for output threads
    float blr = 0.0f;
    if (tid < 136) blr = ldin(blin, tid % PP, f32);

    // ---- stage W_lin^T to LDS, zero h-state, preload x(step 0) ----
    for (int i = tid; i < 50 * PP; i += NTHREADS) {
        int k = i / PP, p = i - k * PP;
        WLt[i] = ldin(wlin, (long)p * 50 + k, f32);
    }
    for (int i = tid; i < 1200; i += NTHREADS) S[136 + i] = 0.0f;  // h1,h2,h3 = 0

    const long rowBase = (long)blockIdx.x * MROWS;
    const long xStride = (long)T * PP;
    if (tid < 136) {
        int m = tid / PP, p = tid - (tid / PP) * PP;
        S[p * MROWS + m] = ldin(x, (rowBase + m) * xStride + p, f32);
    }
    float c1 = 0.0f, c2 = 0.0f, c3 = 0.0f;
    __syncthreads();

    const long outStride = (long)steps * PP;
    for (int s = 0; s < steps; ++s) {
        gate_phase<34>(S, gb, w1, b1, 0, g, half);        // cell1: [x|h1], K=67 (pad 68)
        __syncthreads();
        if (tid < 400) lstm_update(S, gb, c1, 17, tid);   // write h1
        __syncthreads();
        gate_phase<50>(S, gb, w2, b2, 17, g, half);       // cell2: [h1|h2], K=100
        __syncthreads();
        if (tid < 400) lstm_update(S, gb, c2, 67, tid);   // write h2
        __syncthreads();
        gate_phase<50>(S, gb, w3, b3, 67, g, half);       // cell3: [h2|h3], K=100
        __syncthreads();
        if (tid < 400) lstm_update(S, gb, c3, 117, tid);  // write h3
        __syncthreads();
        // ---- linear head + output + next input (feedback or global x) ----
        if (tid < 136) {
            int m = tid / PP, p = tid - (tid / PP) * PP;
            float acc = blr;
#pragma unroll
            for (int k = 0; k < 50; ++k)
                acc = fmaf(WLt[k * PP + p], S[(117 + k) * MROWS + m], acc);
            long oi = (rowBase + m) * outStride + (long)s * PP + p;
            if (f32) ((float*)out)[oi] = acc;
            else     ((unsigned short*)out)[oi] = f2bf(acc);
            if (s + 1 >= T && s + 1 < steps)              // autoregressive feedback
                S[p * MROWS + m] = acc;
        } else if (tid >= 256 && tid < 392) {
            int q = tid - 256;
            int m = q / PP, p = q - (q / PP) * PP;
            if (s + 1 < T)                                // prefetch next x chunk
                S[p * MROWS + m] = ldin(x, (rowBase + m) * xStride + (long)(s + 1) * PP + p, f32);
        }
        __syncthreads();
    }
}

extern "C" void kernel_launch(void* const* d_in, const int* in_sizes, int n_in,
                              void* d_out, int out_size, void* d_ws, size_t ws_size,
                              hipStream_t stream) {
    (void)ws_size; (void)n_in;
    int* flag = (int*)d_ws;

    const int T     = in_sizes[0] / (BATCH * PP);   // 512
    const int steps = out_size / (BATCH * PP);      // 544

    sniff_dtype<<<1, 64, 0, stream>>>((const unsigned short*)d_in[1], flag);

    lstm_persistent<<<NBLOCKS, NTHREADS, 0, stream>>>(
        d_in[0],
        d_in[1], d_in[2], d_in[3], d_in[4],
        d_in[5], d_in[6], d_in[7], d_in[8],
        d_in[9], d_in[10], d_in[11], d_in[12],
        d_in[13], d_in[14],
        d_out, flag, T, steps);
}

// Round 3
// 3807.520 us; speedup vs baseline: 1.0687x; 1.0687x over previous
//
#include <hip/hip_runtime.h>
#include <math.h>

// LSTMPredictor: B=2048 rows, 3x LSTMCell(H=50), P=17, T=512 + 32 future steps.
// fp32 buffers (runtime-sniffed, bf16 fallback kept). One block per CU owns M=8
// batch rows for the whole 544-step recurrence. Weights in per-thread registers;
// thread = (gate-pair g2, K-quarter q) so each broadcast state read feeds 16 fmacs.
// h-state in LDS; c-state in registers of the (m,j) update thread.

#define BATCH    2048
#define PP       17
#define HH       50
#define GG       200      // 4*H
#define MROWS    8
#define NTHREADS 512
#define NBLOCKS  (BATCH / MROWS)   // 256

__device__ __forceinline__ float bf2f(unsigned short u) {
    unsigned int i = ((unsigned int)u) << 16;
    float f; __builtin_memcpy(&f, &i, 4); return f;
}
__device__ __forceinline__ unsigned short f2bf(float f) {
    unsigned int i; __builtin_memcpy(&i, &f, 4);
    return (unsigned short)((i + 0x7fffu + ((i >> 16) & 1u)) >> 16);
}
__device__ __forceinline__ float ldin(const void* p, long i, bool f32) {
    return f32 ? ((const float*)p)[i] : bf2f(((const unsigned short*)p)[i]);
}
// saturation-safe fast sigmoid/tanh (v_exp_f32 + v_rcp_f32)
__device__ __forceinline__ float fsig(float x) {
    float t = exp2f(-1.44269504089f * x);          // +inf at x->-inf, 0 at x->+inf
    return __builtin_amdgcn_rcpf(1.0f + t);        // 0 / 1 at the limits
}
__device__ __forceinline__ float ftanh(float x) {
    float t = exp2f(2.88539008178f * x);           // e^(2x)
    return 1.0f - 2.0f * __builtin_amdgcn_rcpf(t + 1.0f);   // -1 / +1 at the limits
}

// ---- dtype sniffer: bf16 weights decode to |v|<=0.142; fp32-as-bf16 gives junk ----
extern "C" __global__ void sniff_dtype(const unsigned short* __restrict__ w,
                                       int* __restrict__ flag) {
    int lane = threadIdx.x;
    bool bad = false;
#pragma unroll
    for (int t = 0; t < 4; ++t) {
        float v = bf2f(w[lane * 4 + t]);
        bad |= !(fabsf(v) <= 1.0f);
    }
    unsigned long long m = __ballot(bad);
    if (lane == 0) flag[0] = (m != 0ULL) ? 1 : 0;   // 1 => fp32 buffers
}

// gate phase: thread (g2,q) accumulates K-quarter partials of gates {2g2, 2g2+1}
// for all 8 rows. Weights in registers; state read is wave-uniform (broadcast).
template <int TQ>
__device__ __forceinline__ void gate_phase(const float* __restrict__ S,
                                           float* __restrict__ gb,
                                           const float w[2][TQ],
                                           int srow, int g2, int q, bool active) {
    if (active) {
        float aA[8] = {0, 0, 0, 0, 0, 0, 0, 0};
        float aB[8] = {0, 0, 0, 0, 0, 0, 0, 0};
        const float4* Sp = (const float4*)(S + (srow + q * TQ) * MROWS);
#pragma unroll
        for (int t = 0; t < TQ; ++t) {
            float wa = w[0][t], wb = w[1][t];
            float4 lo = Sp[2 * t];         // wave-uniform address -> LDS broadcast
            float4 hi = Sp[2 * t + 1];
            aA[0] = fmaf(wa, lo.x, aA[0]); aA[1] = fmaf(wa, lo.y, aA[1]);
            aA[2] = fmaf(wa, lo.z, aA[2]); aA[3] = fmaf(wa, lo.w, aA[3]);
            aA[4] = fmaf(wa, hi.x, aA[4]); aA[5] = fmaf(wa, hi.y, aA[5]);
            aA[6] = fmaf(wa, hi.z, aA[6]); aA[7] = fmaf(wa, hi.w, aA[7]);
            aB[0] = fmaf(wb, lo.x, aB[0]); aB[1] = fmaf(wb, lo.y, aB[1]);
            aB[2] = fmaf(wb, lo.z, aB[2]); aB[3] = fmaf(wb, lo.w, aB[3]);
            aB[4] = fmaf(wb, hi.x, aB[4]); aB[5] = fmaf(wb, hi.y, aB[5]);
            aB[6] = fmaf(wb, hi.z, aB[6]); aB[7] = fmaf(wb, hi.w, aB[7]);
        }
#pragma unroll
        for (int m = 0; m < 8; ++m) {      // float2 store, gates adjacent
            float2 v; v.x = aA[m]; v.y = aB[m];
            ((float2*)(gb + (q * MROWS + m) * GG))[g2] = v;
        }
    }
}

__device__ __forceinline__ void lstm_update(float* __restrict__ S,
                                            const float* __restrict__ gb,
                                            const float* __restrict__ bs,
                                            float& c, int hrow, int tid) {
    // caller guards tid < 400;  m = tid&7 (conflict-free h write), j = tid>>3
    int m = tid & 7;
    int j = tid >> 3;
    float ii = bs[j], ff = bs[50 + j], gg = bs[100 + j], oo = bs[150 + j];
#pragma unroll
    for (int q = 0; q < 4; ++q) {
        const float* b = gb + (q * MROWS + m) * GG;
        ii += b[j]; ff += b[50 + j]; gg += b[100 + j]; oo += b[150 + j];
    }
    float cn = fsig(ff) * c + fsig(ii) * ftanh(gg);
    c = cn;
    S[(hrow + j) * MROWS + m] = fsig(oo) * ftanh(cn);   // addr = hrow*8 + tid
}

extern "C" __global__ void __launch_bounds__(NTHREADS, 2)
lstm_persistent(const void* __restrict__ x,
                const void* __restrict__ wih1, const void* __restrict__ whh1,
                const void* __restrict__ bih1, const void* __restrict__ bhh1,
                const void* __restrict__ wih2, const void* __restrict__ whh2,
                const void* __restrict__ bih2, const void* __restrict__ bhh2,
                const void* __restrict__ wih3, const void* __restrict__ whh3,
                const void* __restrict__ bih3, const void* __restrict__ bhh3,
                const void* __restrict__ wlin, const void* __restrict__ blin,
                void* __restrict__ out, const int* __restrict__ flag,
                int T, int steps)
{
    const int tid = threadIdx.x;
    __shared__ float S[167 * MROWS];       // 0..16 x | 17..66 h1 | 67..116 h2 | 117..166 h3
    __shared__ float gb[4 * MROWS * GG];   // [quarter][m][gate]
    __shared__ float WLt[50 * PP];         // W_lin^T
    __shared__ float bs1[GG], bs2[GG], bs3[GG], bl[PP];

    const bool f32 = (flag[0] != 0);

    const int q  = tid >> 7;               // wave-uniform K-quarter
    const int g2 = tid & 127;              // gate pair; active if < 100
    const bool active = (g2 < 100);

    // ---- per-thread register weights (fp32, full precision) ----
    float w1[2][17], w2[2][25], w3[2][25];
    if (active) {
#pragma unroll
        for (int e = 0; e < 2; ++e) {
            const int g = 2 * g2 + e;
#pragma unroll
            for (int t = 0; t < 17; ++t) {           // cell1 K=68 (row 67 zero-pad)
                int k = q * 17 + t;
                w1[e][t] = (k < 17) ? ldin(wih1, (long)g * 17 + k, f32)
                         : (k < 67) ? ldin(whh1, (long)g * 50 + (k - 17), f32)
                                    : 0.0f;
            }
#pragma unroll
            for (int t = 0; t < 25; ++t) {           // cell2 K=100
                int k = q * 25 + t;
                w2[e][t] = (k < 50) ? ldin(wih2, (long)g * 50 + k, f32)
                                    : ldin(whh2, (long)g * 50 + (k - 50), f32);
            }
#pragma unroll
            for (int t = 0; t < 25; ++t) {           // cell3 K=100
                int k = q * 25 + t;
                w3[e][t] = (k < 50) ? ldin(wih3, (long)g * 50 + k, f32)
                                    : ldin(whh3, (long)g * 50 + (k - 50), f32);
            }
        }
    }

    // ---- stage biases, W_lin^T, zero h-state, preload x(step 0) ----
    if (tid < GG) {
        bs1[tid] = ldin(bih1, tid, f32) + ldin(bhh1, tid, f32);
        bs2[tid] = ldin(bih2, tid, f32) + ldin(bhh2, tid, f32);
        bs3[tid] = ldin(bih3, tid, f32) + ldin(bhh3, tid, f32);
    } else if (tid < GG + PP) {
        bl[tid - GG] = ldin(blin, tid - GG, f32);
    }
    for (int i = tid; i < 50 * PP; i += NTHREADS) {
        int k = i / PP, p = i - k * PP;
        WLt[i] = ldin(wlin, (long)p * 50 + k, f32);
    }
    for (int i = tid; i < 1200; i += NTHREADS) S[136 + i] = 0.0f;   // h1,h2,h3 = 0

    const long rowBase = (long)blockIdx.x * MROWS;
    const long xStride = (long)T * PP;
    if (tid < 136) {
        int m = tid / PP, p = tid - (tid / PP) * PP;
        S[p * MROWS + m] = ldin(x, (rowBase + m) * xStride + p, f32);
    }
    float c1 = 0.0f, c2 = 0.0f, c3 = 0.0f;
    __syncthreads();

    const long outStride = (long)steps * PP;
    for (int s = 0; s < steps; ++s) {
        gate_phase<17>(S, gb, w1, 0, g2, q, active);            // cell1: [x|h1]
        __syncthreads();
        if (tid < 400) lstm_update(S, gb, bs1, c1, 17, tid);    // write h1
        __syncthreads();
        gate_phase<25>(S, gb, w2, 17, g2, q, active);           // cell2: [h1|h2]
        __syncthreads();
        if (tid < 400) lstm_update(S, gb, bs2, c2, 67, tid);    // write h2
        __syncthreads();
        gate_phase<25>(S, gb, w3, 67, g2, q, active);           // cell3: [h2|h3]
        __syncthreads();
        if (tid < 400) lstm_update(S, gb, bs3, c3, 117, tid);   // write h3
        __syncthreads();
        // ---- linear head + output + next input (feedback or global x) ----
        if (tid < 136) {
            int m = tid / PP, p = tid - (tid / PP) * PP;
            float acc = bl[p];
#pragma unroll
            for (int k = 0; k < 50; ++k)
                acc = fmaf(WLt[k * PP + p], S[(117 + k) * MROWS + m], acc);
            long oi = (rowBase + m) * outStride + (long)s * PP + p;
            if (f32) ((float*)out)[oi] = acc;
            else     ((unsigned short*)out)[oi] = f2bf(acc);
            if (s + 1 >= T && s + 1 < steps)                    // autoregressive feedback
                S[p * MROWS + m] = acc;
        } else if (tid >= 256 && tid < 392) {
            int u = tid - 256;
            int m = u / PP, p = u - (u / PP) * PP;
            if (s + 1 < T)                                      // prefetch next x chunk
                S[p * MROWS + m] = ldin(x, (rowBase + m) * xStride + (long)(s + 1) * PP + p, f32);
        }
        __syncthreads();
    }
}

extern "C" void kernel_launch(void* const* d_in, const int* in_sizes, int n_in,
                              void* d_out, int out_size, void* d_ws, size_t ws_size,
                              hipStream_t stream) {
    (void)ws_size; (void)n_in;
    int* flag = (int*)d_ws;

    const int T     = in_sizes[0] / (BATCH * PP);   // 512
    const int steps = out_size / (BATCH * PP);      // 544

    sniff_dtype<<<1, 64, 0, stream>>>((const unsigned short*)d_in[1], flag);

    lstm_persistent<<<NBLOCKS, NTHREADS, 0, stream>>>(
        d_in[0],
        d_in[1], d_in[2], d_in[3], d_in[4],
        d_in[5], d_in[6], d_in[7], d_in[8],
        d_in[9], d_in[10], d_in[11], d_in[12],
        d_in[13], d_in[14],
        d_out, flag, T, steps);
}